// Round 4
// baseline (1371.673 us; speedup 1.0000x reference)
//
#include <hip/hip_runtime.h>
#include <hip/hip_bf16.h>

typedef __attribute__((ext_vector_type(4))) float f32x4;
typedef __attribute__((ext_vector_type(8))) short short8;
typedef __attribute__((ext_vector_type(8))) __bf16 bf16x8;

union FragU { bf16x8 h; short8 s; };

typedef const __attribute__((address_space(1))) void gvoid_t;
typedef __attribute__((address_space(3))) void lvoid_t;

static __device__ __forceinline__ void gload16(const void* g, void* l) {
  // async global->LDS, 16B per lane; LDS dest is wave-uniform base + lane*16
  __builtin_amdgcn_global_load_lds((gvoid_t*)g, (lvoid_t*)l, 16, 0, 0);
}

// ---------------------------------------------------------------------------
// One-time adjacency convert: f32 row-major A[M][K] -> bf16 tiled cache
//   cache[rowblk][ktile64][g' (k-granule 0..7)][row 0..127][8 bf16]
// Tile = 128 rows x 64 k = 16384 B. Ragged K zero-padded. Sequential writes;
// reads are 1-KB row strips staged through a 64 KB LDS tile (4 ktiles/block).
// ---------------------------------------------------------------------------
__global__ __launch_bounds__(256) void convert_tile(
    const float* __restrict__ Au, __bf16* __restrict__ Cu,
    const float* __restrict__ Am, __bf16* __restrict__ Cm, int nbU)
{
  __shared__ __bf16 tile[32768];   // 64 KB: [kt(4)][g'(8)][row(128)][8]
  const int t = threadIdx.x;

  const float* A; __bf16* Cc; int M, K, KT, rb, kg;
  {
    int bx = blockIdx.x;
    if (bx < nbU) { A = Au; Cc = Cu; M = 20000; K = 10000; KT = 157; rb = bx % 157; kg = bx / 157; }
    else { int b2 = bx - nbU; A = Am; Cc = Cm; M = 10000; K = 20000; KT = 313; rb = b2 % 79; kg = b2 / 79; }
  }
  const int t0  = kg * 4;
  const int tig = min(4, KT - t0);
  const int kBase = t0 * 64;

  int row = rb * 128 + (t >> 1); if (row > M - 1) row = M - 1;
  const int sub = t & 1;
  const float* rp = A + (size_t)row * K;

  for (int j = 0; j < 16; ++j) {
    int kLocal = sub * 128 + j * 8;
    if (kLocal >= tig * 64) break;
    int kAbs = kBase + kLocal;
    FragU u;
    if (kAbs < K) {              // 8-granules all-in/out (8 | K)
      f32x4 a0 = *(const f32x4*)(rp + kAbs);
      f32x4 a1 = *(const f32x4*)(rp + kAbs + 4);
      bf16x8 h;
      h[0] = (__bf16)a0[0]; h[1] = (__bf16)a0[1];
      h[2] = (__bf16)a0[2]; h[3] = (__bf16)a0[3];
      h[4] = (__bf16)a1[0]; h[5] = (__bf16)a1[1];
      h[6] = (__bf16)a1[2]; h[7] = (__bf16)a1[3];
      u.h = h;
    } else {
      u.s = (short8){0,0,0,0,0,0,0,0};
    }
    // LDS slot (elems): kt*8192 + g'*1024 + rowLocal*8
    *(short8*)&tile[(kLocal >> 6) * 8192 + ((kLocal >> 3) & 7) * 1024 + (t >> 1) * 8] = u.s;
  }
  __syncthreads();

  __bf16* outp = Cc + ((size_t)rb * KT + t0) * 8192;   // elems
  const int nch = tig * 4;                              // 4096-B chunks
  for (int c = 0; c < nch; ++c)
    *(short8*)(outp + c * 2048 + t * 8) = *(const short8*)&tile[c * 2048 + t * 8];
}

// ---------------------------------------------------------------------------
// Fused bf16 GEMM pair over tiled A-cache:
//   P[split][M][64] = Acache[M][ktiles] @ BT[64][Kpad]^T   (both bf16)
// 128 rows x 64 cols/block, BK=64 (ktile), 2-buffer LDS via global_load_lds
// (A staging is a linear 16-KB tile copy). Plain stores to per-split partials.
// ---------------------------------------------------------------------------
__global__ __launch_bounds__(256) void gemm_bf16(
    const __bf16* __restrict__ Acu, const __bf16* __restrict__ BTu,
    float* __restrict__ Pu, int Mu, int KTu, int padKu,
    const __bf16* __restrict__ Acm, const __bf16* __restrict__ BTm,
    float* __restrict__ Pm, int Mm, int KTm, int padKm,
    int nbU, int rbU, int rbM)
{
  __shared__ __bf16 sA[2][8192];   // 2 x 16 KB  [g'(8)][row(128)][8]
  __shared__ __bf16 sB[2][4096];   // 2 x  8 KB  [g'(8)][row(64)][8]

  const int t = threadIdx.x;
  const int w = t >> 6;
  const int lane = t & 63;
  const int r = lane & 15;
  const int g = lane >> 4;

  const __bf16 *Ac, *BT; float* P; int M, KT, Kpad, rowBlk, split;
  {
    int bx = blockIdx.x;
    if (bx < nbU) {
      Ac = Acu; BT = BTu; P = Pu; M = Mu; KT = KTu; Kpad = padKu;
      rowBlk = bx % rbU; split = bx / rbU;
    } else {
      int b2 = bx - nbU;
      Ac = Acm; BT = BTm; P = Pm; M = Mm; KT = KTm; Kpad = padKm;
      rowBlk = b2 % rbM; split = b2 / rbM;
    }
  }
  const int rowBase = rowBlk * 128;
  const int tLo = split * 20;
  const int nt = min(20, KT - tLo);

  f32x4 acc[2][4];
  #pragma unroll
  for (int m = 0; m < 2; ++m)
    #pragma unroll
    for (int n = 0; n < 4; ++n)
      acc[m][n] = (f32x4){0.f, 0.f, 0.f, 0.f};

  auto stage = [&](int buf, int tt) {
    const __bf16* tp = Ac + ((size_t)rowBlk * KT + tt) * 8192;
    #pragma unroll
    for (int i = 0; i < 4; ++i)
      gload16(tp + i * 2048 + w * 512 + lane * 8, &sA[buf][i * 2048 + w * 512]);
    #pragma unroll
    for (int i = 0; i < 2; ++i) {
      int lin = i * 256 + t;
      int kg = lin >> 6, brow = lin & 63;
      gload16(BT + (size_t)brow * Kpad + tt * 64 + kg * 8,
              &sB[buf][i * 2048 + w * 512]);
    }
  };

  int cur = 0;
  stage(0, tLo);
  __syncthreads();

  for (int tt = 0; tt < nt; ++tt) {
    if (tt + 1 < nt) stage(cur ^ 1, tLo + tt + 1);
    #pragma unroll
    for (int ks = 0; ks < 2; ++ks) {
      const int kgo = ks * 4 + g;
      FragU aF[2], bF[4];
      #pragma unroll
      for (int m = 0; m < 2; ++m)
        aF[m].s = *(const short8*)&sA[cur][kgo * 1024 + (w * 32 + m * 16 + r) * 8];
      #pragma unroll
      for (int n = 0; n < 4; ++n)
        bF[n].s = *(const short8*)&sB[cur][kgo * 512 + (n * 16 + r) * 8];
      #pragma unroll
      for (int m = 0; m < 2; ++m)
        #pragma unroll
        for (int n = 0; n < 4; ++n)
          acc[m][n] = __builtin_amdgcn_mfma_f32_16x16x32_bf16(
              aF[m].s, bF[n].s, acc[m][n], 0, 0, 0);
    }
    __syncthreads();
    cur ^= 1;
  }

  // epilogue: C/D layout col = lane&15, row = (lane>>4)*4 + reg
  float* Pp = P + (size_t)split * M * 64;
  #pragma unroll
  for (int m = 0; m < 2; ++m) {
    #pragma unroll
    for (int j = 0; j < 4; ++j) {
      const int row = rowBase + w * 32 + m * 16 + g * 4 + j;
      if (row < M) {
        #pragma unroll
        for (int n = 0; n < 4; ++n)
          Pp[(size_t)row * 64 + n * 16 + r] = acc[m][n][j];
      }
    }
  }
}

// ---------------------------------------------------------------------------
// Transpose + f32->bf16 convert with K padding:
//   in[K][64] f32 -> out[64][Kpad] bf16 (pad region zero-filled)
// ---------------------------------------------------------------------------
__global__ __launch_bounds__(256) void transpose_cvt(
    const float* __restrict__ in, __bf16* __restrict__ out, int K, int Kpad)
{
  __shared__ float tile[64][65];
  const int t = threadIdx.x;
  const int k0 = blockIdx.x * 64;
  #pragma unroll
  for (int i = 0; i < 4; ++i) {
    int f = t + i * 256;
    int k = f >> 4;
    int cc = (f & 15) << 2;
    if (k0 + k < K) {
      f32x4 v = *(const f32x4*)(in + (size_t)(k0 + k) * 64 + cc);
      tile[k][cc + 0] = v[0]; tile[k][cc + 1] = v[1];
      tile[k][cc + 2] = v[2]; tile[k][cc + 3] = v[3];
    }
  }
  __syncthreads();
  const int c = t >> 2;
  const int kc = (t & 3) << 4;
  #pragma unroll
  for (int h = 0; h < 2; ++h) {
    int kk = kc + h * 8;
    FragU p;
    if (k0 + kk < K) {           // 8-granules all-in/out (8 | K)
      #pragma unroll
      for (int j = 0; j < 8; ++j) p.h[j] = (__bf16)tile[kk + j][c];
    } else {
      p.s = (short8){0,0,0,0,0,0,0,0};
    }
    *(short8*)(out + (size_t)c * Kpad + k0 + kk) = p.s;
  }
}

// ---------------------------------------------------------------------------
// out[i][c] = LeakyReLU( (sum_s P[s][i][:] + self[i][:]) . W[c][:] + 2*b[c] )
// ---------------------------------------------------------------------------
__global__ __launch_bounds__(256) void layer_reduce(
    const float* __restrict__ P, int S,
    const float* __restrict__ self, const float* __restrict__ W,
    const float* __restrict__ b, float* __restrict__ out, int M)
{
  __shared__ float xs[4][64];
  const int t = threadIdx.x;
  const int c = t & 63;
  const int grp = t >> 6;
  const int row = blockIdx.x * 4 + grp;
  if (row < M) {
    float x = self[(size_t)row * 64 + c];
    for (int s = 0; s < S; ++s)
      x += P[(size_t)s * M * 64 + (size_t)row * 64 + c];
    xs[grp][c] = x;
  }
  __syncthreads();
  if (row >= M) return;
  float acc = 0.f;
  const f32x4* Wc = (const f32x4*)(W + c * 64);
  #pragma unroll
  for (int k4 = 0; k4 < 16; ++k4) {
    f32x4 wv = Wc[k4];
    acc += xs[grp][k4 * 4 + 0] * wv[0] + xs[grp][k4 * 4 + 1] * wv[1]
         + xs[grp][k4 * 4 + 2] * wv[2] + xs[grp][k4 * 4 + 3] * wv[3];
  }
  float v = acc + 2.0f * b[c];
  out[(size_t)row * 64 + c] = (v > 0.f) ? v : 0.01f * v;
}

// ---------------------------------------------------------------------------
__global__ __launch_bounds__(256) void gather_score(
    const int* __restrict__ uid, const int* __restrict__ mid,
    const float* __restrict__ u0, const float* __restrict__ u1,
    const float* __restrict__ u2, const float* __restrict__ u3,
    const float* __restrict__ m0, const float* __restrict__ m1,
    const float* __restrict__ m2, const float* __restrict__ m3,
    const float* __restrict__ oW, const float* __restrict__ ob,
    float* __restrict__ scores, int B)
{
  const int wave = threadIdx.x >> 6;
  const int lane = threadIdx.x & 63;
  const int b = blockIdx.x * 4 + wave;
  if (b >= B) return;
  const size_t ub = (size_t)uid[b] * 64 + lane;
  const size_t mb = (size_t)mid[b] * 64 + lane;
  float acc = u0[ub] * m0[mb] * oW[lane]
            + u1[ub] * m1[mb] * oW[64 + lane]
            + u2[ub] * m2[mb] * oW[128 + lane]
            + u3[ub] * m3[mb] * oW[192 + lane];
  #pragma unroll
  for (int off = 32; off > 0; off >>= 1)
    acc += __shfl_down(acc, off, 64);
  if (lane == 0) scores[b] = acc + ob[0];
}

// ---------------------------------------------------------------------------
extern "C" void kernel_launch(void* const* d_in, const int* in_sizes, int n_in,
                              void* d_out, int out_size, void* d_ws, size_t ws_size,
                              hipStream_t stream)
{
  const float* user_adj  = (const float*)d_in[0];
  const float* movie_adj = (const float*)d_in[1];
  const int*   user_id   = (const int*)d_in[2];
  const int*   movie_id  = (const int*)d_in[3];
  const float* user_emb  = (const float*)d_in[4];
  const float* movie_emb = (const float*)d_in[5];
  const float* user_Ws   = (const float*)d_in[6];
  const float* user_bs   = (const float*)d_in[7];
  const float* movie_Ws  = (const float*)d_in[8];
  const float* movie_bs  = (const float*)d_in[9];
  const float* out_W     = (const float*)d_in[10];
  const float* out_b     = (const float*)d_in[11];

  const int NU = 20000, NM = 10000, E = 64, B = 8192;
  const int rbU = 157, rbM = 79;          // ceil(NU/128), ceil(NM/128)
  const int KT_U = 157, KT_M = 313;       // ceil(NM/64), ceil(NU/64)
  const int NMpad = KT_U * 64;            // 10048 (user-gemm K pad)
  const int NUpad = KT_M * 64;            // 20032 (movie-gemm K pad)
  const int SU = 8, SM = 16;              // k-splits (20 ktiles each)

  char* ws = (char*)d_ws;
  size_t o = 0;
  __bf16* Au_c = (__bf16*)(ws + o); o += (size_t)rbU * KT_U * 16384;  // 403,849,216
  __bf16* Am_c = (__bf16*)(ws + o); o += (size_t)rbM * KT_M * 16384;  // 405,143,552
  float*  uP   = (float*)(ws + o);  o += (size_t)SU * NU * 64 * 4;    //  40,960,000
  float*  mP   = (float*)(ws + o);  o += (size_t)SM * NM * 64 * 4;    //  40,960,000
  float*  u1   = (float*)(ws + o);  o += (size_t)NU * 64 * 4;
  float*  u2   = (float*)(ws + o);  o += (size_t)NU * 64 * 4;
  float*  m1   = (float*)(ws + o);  o += (size_t)NM * 64 * 4;
  float*  m2   = (float*)(ws + o);  o += (size_t)NM * 64 * 4;
  __bf16* uT   = (__bf16*)(ws + o); o += (size_t)64 * NUpad * 2;
  __bf16* mT   = (__bf16*)(ws + o); o += (size_t)64 * NMpad * 2;

  float* scores = (float*)d_out;
  float* u3 = scores + B;
  float* m3 = u3 + (size_t)NU * E;

  // one-time tiled bf16 conversion of both adjacency matrices
  const int cbU = rbU * ((KT_U + 3) / 4);   // 157*40 = 6280
  const int cbM = rbM * ((KT_M + 3) / 4);   // 79*79  = 6241
  convert_tile<<<cbU + cbM, 256, 0, stream>>>(user_adj, Au_c, movie_adj, Am_c, cbU);

  const int nbU = rbU * SU;   // 1256
  const int nbM = rbM * SM;   // 1264

  const float* uCur = user_emb;
  const float* mCur = movie_emb;
  for (int l = 0; l < 3; ++l) {
    float* uNext = (l == 0) ? u1 : (l == 1) ? u2 : u3;
    float* mNext = (l == 0) ? m1 : (l == 1) ? m2 : m3;

    transpose_cvt<<<NMpad / 64, 256, 0, stream>>>(mCur, mT, NM, NMpad);
    transpose_cvt<<<NUpad / 64, 256, 0, stream>>>(uCur, uT, NU, NUpad);

    gemm_bf16<<<nbU + nbM, 256, 0, stream>>>(
        Au_c, mT, uP, NU, KT_U, NMpad,
        Am_c, uT, mP, NM, KT_M, NUpad,
        nbU, rbU, rbM);

    layer_reduce<<<(NU + 3) / 4, 256, 0, stream>>>(
        uP, SU, uCur, user_Ws + (size_t)l * E * E, user_bs + (size_t)l * E, uNext, NU);
    layer_reduce<<<(NM + 3) / 4, 256, 0, stream>>>(
        mP, SM, mCur, movie_Ws + (size_t)l * E * E, movie_bs + (size_t)l * E, mNext, NM);
    uCur = uNext; mCur = mNext;
  }
  gather_score<<<(B + 3) / 4, 256, 0, stream>>>(
      user_id, movie_id, user_emb, u1, u2, u3,
      movie_emb, m1, m2, m3, out_W, out_b, scores, B);
}